// Round 1
// baseline (499.338 us; speedup 1.0000x reference)
//
#include <hip/hip_runtime.h>

#define NQ 12
#define DIM 4096          // 2^12 amplitudes
#define NLAYERS 6
#define TPB 256
#define XROW 150528       // 3*224*224

__global__ __launch_bounds__(TPB) void qnn_kernel(
    const float* __restrict__ x,      // (512, 150528) — only first 12 per row used
    const float* __restrict__ w,      // (6, 12, 3)
    const float* __restrict__ bias,   // scalar
    float* __restrict__ out)          // (512)
{
    __shared__ float re[DIM];
    __shared__ float im[DIM];
    __shared__ float partial[TPB / 64];

    const int b   = blockIdx.x;
    const int tid = threadIdx.x;

    // |0...0>
    for (int i = tid; i < DIM; i += TPB) { re[i] = 0.f; im[i] = 0.f; }
    if (tid == 0) re[0] = 1.f;
    __syncthreads();

    const float* xb = x + (size_t)b * XROW;

    // ---- AngleEmbedding: RX(x[b, j]) on wire j ----
    // wire j <-> bit position (11 - j); flat C-order, wire 0 = MSB
    for (int j = 0; j < NQ; ++j) {
        const float half = xb[j] * 0.5f;
        const float c = cosf(half);
        const float s = sinf(half);
        const int bp = NQ - 1 - j;
        const int stride = 1 << bp;
        for (int p = tid; p < DIM / 2; p += TPB) {
            const int i0 = ((p >> bp) << (bp + 1)) | (p & (stride - 1));
            const int i1 = i0 + stride;
            const float r0 = re[i0], m0 = im[i0];
            const float r1 = re[i1], m1 = im[i1];
            // U = [[c, -i s], [-i s, c]]
            re[i0] = c * r0 + s * m1;
            im[i0] = c * m0 - s * r1;
            re[i1] = c * r1 + s * m0;
            im[i1] = c * m1 - s * r0;
        }
        __syncthreads();
    }

    // ---- layers: Rot on each wire, then CNOT ring ----
    for (int l = 0; l < NLAYERS; ++l) {
        for (int j = 0; j < NQ; ++j) {
            const float* wj = w + ((l * NQ) + j) * 3;
            const float phi = wj[0], theta = wj[1], omega = wj[2];
            const float ct = cosf(theta * 0.5f);
            const float st = sinf(theta * 0.5f);
            const float sp = 0.5f * (phi + omega);
            const float dm = 0.5f * (phi - omega);
            const float csp = cosf(sp), ssp = sinf(sp);
            const float cdm = cosf(dm), sdm = sinf(dm);
            // Rot = [[a, b], [cc, d]]  (PennyLane RZ(omega)RY(theta)RZ(phi))
            const float ar =  csp * ct, ai = -ssp * ct;   // a = e^{-i sp} ct
            const float br = -cdm * st, bi = -sdm * st;   // b = -e^{+i dm} st
            const float cr =  cdm * st, ci = -sdm * st;   // cc = e^{-i dm} st
            const float dr =  csp * ct, di =  ssp * ct;   // d = e^{+i sp} ct
            const int bp = NQ - 1 - j;
            const int stride = 1 << bp;
            for (int p = tid; p < DIM / 2; p += TPB) {
                const int i0 = ((p >> bp) << (bp + 1)) | (p & (stride - 1));
                const int i1 = i0 + stride;
                const float r0 = re[i0], m0 = im[i0];
                const float r1 = re[i1], m1 = im[i1];
                re[i0] = ar * r0 - ai * m0 + br * r1 - bi * m1;
                im[i0] = ar * m0 + ai * r0 + br * m1 + bi * r1;
                re[i1] = cr * r0 - ci * m0 + dr * r1 - di * m1;
                im[i1] = cr * m0 + ci * r0 + dr * m1 + di * r1;
            }
            __syncthreads();
        }
        for (int j = 0; j < NQ; ++j) {
            const int c_bp = NQ - 1 - j;
            const int t_bp = NQ - 1 - ((j + 1) % NQ);
            const int cbit = 1 << c_bp, tbit = 1 << t_bp;
            const int hi = c_bp > t_bp ? c_bp : t_bp;
            const int lo = c_bp > t_bp ? t_bp : c_bp;
            for (int p = tid; p < DIM / 4; p += TPB) {
                // expand p's 10 bits into positions {0..11} \ {lo, hi}
                int idx = p;
                int low = idx & ((1 << lo) - 1);
                idx = ((idx >> lo) << (lo + 1)) | low;
                low = idx & ((1 << hi) - 1);
                idx = ((idx >> hi) << (hi + 1)) | low;
                const int i0 = idx | cbit;        // ctrl=1, tgt=0
                const int i1 = i0 | tbit;         // ctrl=1, tgt=1
                const float r0 = re[i0], m0 = im[i0];
                re[i0] = re[i1]; im[i0] = im[i1];
                re[i1] = r0;     im[i1] = m0;
            }
            __syncthreads();
        }
    }

    // ---- <Z_0> = sum_{bit11=0} |amp|^2 - sum_{bit11=1} |amp|^2 ----
    float acc = 0.f;
    for (int i = tid; i < DIM; i += TPB) {
        const float p = re[i] * re[i] + im[i] * im[i];
        acc += (i & (1 << (NQ - 1))) ? -p : p;
    }
    #pragma unroll
    for (int off = 32; off > 0; off >>= 1)
        acc += __shfl_down(acc, off, 64);
    const int wave = tid >> 6;
    const int lane = tid & 63;
    if (lane == 0) partial[wave] = acc;
    __syncthreads();
    if (tid == 0) {
        float s = 0.f;
        #pragma unroll
        for (int i = 0; i < TPB / 64; ++i) s += partial[i];
        out[b] = s + bias[0];
    }
}

extern "C" void kernel_launch(void* const* d_in, const int* in_sizes, int n_in,
                              void* d_out, int out_size, void* d_ws, size_t ws_size,
                              hipStream_t stream) {
    const float* x    = (const float*)d_in[0];
    const float* wts  = (const float*)d_in[1];
    const float* bias = (const float*)d_in[2];
    float* out = (float*)d_out;
    qnn_kernel<<<out_size, TPB, 0, stream>>>(x, wts, bias, out);
}